// Round 10
// baseline (155.019 us; speedup 1.0000x reference)
//
#include <hip/hip_runtime.h>

// LinearGaussianTree, MI355X. 8192 rows; per row a 4095-node binary tree:
// s_i = w_i * s_parent + (1-w_i)*SCALE*noise_i. Outputs fp32 flat:
// samples (8192x4095), ms (8192x4094), scales (8192x4094), reverse level
// order; root = samples col 4094. Column identity: parent = (c>>1)+2048.
//
// r10 = r5 (best, 120.4 us) + NONTEMPORAL hints only:
//   nt-loads for the read-once noise stream, nt-stores for all three
//   write-once output streams (no L2/L3 allocation). Table loads stay cached.

constexpr int   kRows  = 8192;
constexpr float kScale = 0.1f;

typedef float f4_ __attribute__((ext_vector_type(4)));
typedef float f2_ __attribute__((ext_vector_type(2)));
typedef f4_ f4u __attribute__((aligned(4)));   // 16B vector, 4B-aligned ok
typedef f2_ f2u __attribute__((aligned(4)));

// Column-ordered (w, sc) table. Zero-init BSS; rewritten every launch.
__device__ __align__(16) float2 g_tab[4096];

__global__ __launch_bounds__(256) void lgt_precompute(
    const float* __restrict__ weights)
{
    int t = blockIdx.x * 256 + threadIdx.x;      // tree index 0..4093
    if (t < 4094) {
        int d = 31 - __clz(t + 2);               // level of node t
        int c = t + 4098 - 3 * (1 << d);         // output column
        float w = 1.0f / (1.0f + __expf(-weights[t]));
        g_tab[c] = make_float2(w, (1.0f - w) * kScale);
    }
}

// Barrier that does NOT drain vmcnt (LDS visibility only).
__device__ __forceinline__ void lgkm_barrier() {
    __builtin_amdgcn_sched_barrier(0);
    asm volatile("s_waitcnt lgkmcnt(0)" ::: "memory");
    __builtin_amdgcn_s_barrier();
    __builtin_amdgcn_sched_barrier(0);
}

// Nontemporal helpers.
__device__ __forceinline__ float ntl(const float* p) {
    return __builtin_nontemporal_load(p);
}
__device__ __forceinline__ f2_ ntl2(const float* p) {
    return __builtin_nontemporal_load((const f2u*)p);
}
__device__ __forceinline__ void nts(float* p, float v) {
    __builtin_nontemporal_store(v, p);
}
__device__ __forceinline__ void nts2(float* p, f2_ v) {
    __builtin_nontemporal_store(v, (f2u*)p);
}
__device__ __forceinline__ void nts4(float* p, f4_ v) {
    __builtin_nontemporal_store(v, (f4u*)p);
}

__global__ __launch_bounds__(256) void lgt_main(
    const float* __restrict__ noise_root,
    const float* __restrict__ noise_rest,
    float* __restrict__ samples,
    float* __restrict__ ms,
    float* __restrict__ scales)
{
    __shared__ float sL[256];                    // cols 3840..4095 (root @254)

    const int row = blockIdx.x;
    const int tid = threadIdx.x;
    const float* __restrict__ nr = noise_rest + (size_t)row * 4094;
    float* __restrict__ sr = samples + (size_t)row * 4095;
    float* __restrict__ mr = ms      + (size_t)row * 4094;
    float* __restrict__ cr = scales  + (size_t)row * 4094;

    // ---- prefetch all of this row's noise (nt: read-once stream) ----
    const float nzs = ntl(nr + tid);             // levels 1..7
    const float n8  = ntl(nr + 254 + tid);       // level 8
    const f2_  n9   = ntl2(nr + 510 + 2 * tid);
    const f2_  nA0  = ntl2(nr + 1022 + 4 * tid);
    const f2_  nA1  = ntl2(nr + 1022 + 4 * tid + 2);
    f2_ nL[4];
    #pragma unroll
    for (int k = 0; k < 4; ++k)
        nL[k] = ntl2(nr + 2046 + 8 * tid + 2 * k);
    const float rootv = ntl(noise_root + row);   // IN_SCALE == 1.0

    if (tid == 0) { sL[254] = rootv; nts(sr + 4094, rootv); }
    lgkm_barrier();

    // ---- phase A: levels 1..7 in LDS (lgkm-only barriers) ----
    #pragma unroll
    for (int d = 1; d <= 7; ++d) {
        const int off     = (1 << d) - 2;
        const int n       = 1 << d;
        const int colbase = 4096 - (n << 1);
        if (tid >= off && tid < off + n) {
            const int c = colbase + (tid - off);
            const float2 t2 = g_tab[c];
            const float  p  = sL[(c >> 1) - 1792];   // parent col - 3840
            const float  mv = t2.x * p;
            const float  v  = fmaf(t2.y, nzs, mv);
            sL[c - 3840] = v;
            nts(sr + c, v); nts(mr + c, mv); nts(cr + c, t2.y);
        }
        lgkm_barrier();
    }

    // ---- phase B: per-thread subtree (levels 8..11), barrier-free ----
    const float a7 = sL[tid >> 1];               // level-7 ancestor

    // level 8: node tid, col 3584+tid
    const float2 t8 = g_tab[3584 + tid];
    const float  m8 = t8.x * a7;
    const float  v8 = fmaf(t8.y, n8, m8);
    nts(sr + 3584 + tid, v8); nts(mr + 3584 + tid, m8); nts(cr + 3584 + tid, t8.y);

    // level 9: cols 3072+2t (contiguous 2)
    const f4_ t9 = *(const f4_*)(&g_tab[3072 + 2 * tid]);   // 16B-aligned
    const float m90 = t9.x * v8, m91 = t9.z * v8;
    const float v90 = fmaf(t9.y, n9.x, m90);
    const float v91 = fmaf(t9.w, n9.y, m91);
    {
        f2_ sv; sv.x = v90; sv.y = v91;
        f2_ mv; mv.x = m90; mv.y = m91;
        f2_ cv; cv.x = t9.y; cv.y = t9.w;
        nts2(sr + 3072 + 2 * tid, sv);
        nts2(mr + 3072 + 2 * tid, mv);
        nts2(cr + 3072 + 2 * tid, cv);
    }

    // level 10: cols 2048+4t (contiguous 4)
    const f4_ tA = *(const f4_*)(&g_tab[2048 + 4 * tid]);
    const f4_ tB = *(const f4_*)(&g_tab[2048 + 4 * tid + 2]);
    const float mA0 = tA.x * v90, mA1 = tA.z * v90;
    const float mA2 = tB.x * v91, mA3 = tB.z * v91;
    const float vA0 = fmaf(tA.y, nA0.x, mA0);
    const float vA1 = fmaf(tA.w, nA0.y, mA1);
    const float vA2 = fmaf(tB.y, nA1.x, mA2);
    const float vA3 = fmaf(tB.w, nA1.y, mA3);
    {
        f4_ sv; sv.x = vA0; sv.y = vA1; sv.z = vA2; sv.w = vA3;
        f4_ mv; mv.x = mA0; mv.y = mA1; mv.z = mA2; mv.w = mA3;
        f4_ cv; cv.x = tA.y; cv.y = tA.w; cv.z = tB.y; cv.w = tB.w;
        nts4(sr + 2048 + 4 * tid, sv);
        nts4(mr + 2048 + 4 * tid, mv);
        nts4(cr + 2048 + 4 * tid, cv);
    }

    // level 11: cols 8t (contiguous 8)
    const float pv[4] = { vA0, vA1, vA2, vA3 };
    float sv[8], mv[8], cv[8];
    #pragma unroll
    for (int k = 0; k < 4; ++k) {
        const f4_  t = *(const f4_*)(&g_tab[8 * tid + 2 * k]);  // 16B-aligned
        const float p = pv[k];
        const float m0 = t.x * p, m1 = t.z * p;
        sv[2 * k]     = fmaf(t.y, nL[k].x, m0);
        sv[2 * k + 1] = fmaf(t.w, nL[k].y, m1);
        mv[2 * k] = m0; mv[2 * k + 1] = m1;
        cv[2 * k] = t.y; cv[2 * k + 1] = t.w;
    }
    {
        f4_ a, b;
        a.x = sv[0]; a.y = sv[1]; a.z = sv[2]; a.w = sv[3];
        b.x = sv[4]; b.y = sv[5]; b.z = sv[6]; b.w = sv[7];
        nts4(sr + 8 * tid,     a);
        nts4(sr + 8 * tid + 4, b);
        a.x = mv[0]; a.y = mv[1]; a.z = mv[2]; a.w = mv[3];
        b.x = mv[4]; b.y = mv[5]; b.z = mv[6]; b.w = mv[7];
        nts4(mr + 8 * tid,     a);
        nts4(mr + 8 * tid + 4, b);
        a.x = cv[0]; a.y = cv[1]; a.z = cv[2]; a.w = cv[3];
        b.x = cv[4]; b.y = cv[5]; b.z = cv[6]; b.w = cv[7];
        nts4(cr + 8 * tid,     a);
        nts4(cr + 8 * tid + 4, b);
    }
}

extern "C" void kernel_launch(void* const* d_in, const int* in_sizes, int n_in,
                              void* d_out, int out_size, void* d_ws, size_t ws_size,
                              hipStream_t stream)
{
    const float* weights    = (const float*)d_in[0];
    const float* noise_root = (const float*)d_in[1];
    const float* noise_rest = (const float*)d_in[2];

    float* out     = (float*)d_out;
    float* samples = out;
    float* ms      = samples + (size_t)kRows * 4095;
    float* scales  = ms      + (size_t)kRows * 4094;

    lgt_precompute<<<(4094 + 255) / 256, 256, 0, stream>>>(weights);
    lgt_main<<<kRows, 256, 0, stream>>>(noise_root, noise_rest,
                                        samples, ms, scales);
}

// Round 11
// 123.700 us; speedup vs baseline: 1.2532x; 1.2532x over previous
//
#include <hip/hip_runtime.h>

// LinearGaussianTree, MI355X. 8192 rows; per row a 4095-node binary tree:
// s_i = w_i * s_parent + (1-w_i)*SCALE*noise_i. Outputs fp32 flat:
// samples (8192x4095), ms (8192x4094), scales (8192x4094), reverse level
// order; root = samples col 4094. Column identity: parent = (c>>1)+2048.
//
// r11: ONE fused kernel. 2048 blocks x 256 threads; each block owns 4
// consecutive rows, processed sequentially with r5's structure per row
// (phase A: levels 1..7 in LDS with lgkm-only barriers; phase B: per-thread
// register subtrees for levels 8..11). Sigmoids computed from weights ONCE
// per block (no table, no precompute kernel, single dispatch). Row i+1's
// noise prefetch overlaps row i's store drain (no vmcnt waits anywhere).

constexpr int   kRows   = 8192;
constexpr int   kRPB    = 4;       // rows per block
constexpr float kScale  = 0.1f;

typedef float f4_ __attribute__((ext_vector_type(4)));
typedef float f2_ __attribute__((ext_vector_type(2)));
typedef f4_ f4u __attribute__((aligned(4)));   // 16B vector, 4B-aligned ok
typedef f2_ f2u __attribute__((aligned(4)));

__device__ __forceinline__ float sigm(float x) {
    return 1.0f / (1.0f + __expf(-x));
}

// Barrier that does NOT drain vmcnt (LDS visibility only).
__device__ __forceinline__ void lgkm_barrier() {
    __builtin_amdgcn_sched_barrier(0);
    asm volatile("s_waitcnt lgkmcnt(0)" ::: "memory");
    __builtin_amdgcn_s_barrier();
    __builtin_amdgcn_sched_barrier(0);
}

__global__ __launch_bounds__(256) void lgt_fused(
    const float* __restrict__ weights,
    const float* __restrict__ noise_root,
    const float* __restrict__ noise_rest,
    float* __restrict__ samples,
    float* __restrict__ ms,
    float* __restrict__ scales)
{
    __shared__ float sL[256];        // current row's top: L7 at [0..127],
                                     // L1..L6 at [128..253], root at [254]
    const int tid = threadIdx.x;

    // ---- once per block: sigmoids for every node this thread touches ----
    // phase A node: tree idx tid (active iff tid < 254)
    const float wA  = sigm(weights[tid < 254 ? tid : 0]);
    const float scA = (1.0f - wA) * kScale;

    // phase B subtree: L8 node tid; L9 2t,2t+1; L10 4t..; L11 8t.. (tree idx)
    const float wt8  = weights[254 + tid];
    const f2_  wt9  = *(const f2_*)(weights + 510 + 2 * tid);
    const f2_  wtA0 = *(const f2_*)(weights + 1022 + 4 * tid);
    const f2_  wtA1 = *(const f2_*)(weights + 1022 + 4 * tid + 2);
    f2_ wtB[4];
    #pragma unroll
    for (int k = 0; k < 4; ++k)
        wtB[k] = *(const f2_*)(weights + 2046 + 8 * tid + 2 * k);

    const float w8 = sigm(wt8),   c8 = (1.0f - w8) * kScale;
    const float w90 = sigm(wt9.x), c90 = (1.0f - w90) * kScale;
    const float w91 = sigm(wt9.y), c91 = (1.0f - w91) * kScale;
    const float wa0 = sigm(wtA0.x), ca0 = (1.0f - wa0) * kScale;
    const float wa1 = sigm(wtA0.y), ca1 = (1.0f - wa1) * kScale;
    const float wa2 = sigm(wtA1.x), ca2 = (1.0f - wa2) * kScale;
    const float wa3 = sigm(wtA1.y), ca3 = (1.0f - wa3) * kScale;
    float wb[8], cb[8];
    #pragma unroll
    for (int k = 0; k < 4; ++k) {
        wb[2 * k]     = sigm(wtB[k].x); cb[2 * k]     = (1.0f - wb[2 * k]) * kScale;
        wb[2 * k + 1] = sigm(wtB[k].y); cb[2 * k + 1] = (1.0f - wb[2 * k + 1]) * kScale;
    }

    const int row0 = blockIdx.x * kRPB;

    for (int rr = 0; rr < kRPB; ++rr) {
        const int row = row0 + rr;
        const float* __restrict__ nr = noise_rest + (size_t)row * 4094;
        float* __restrict__ sr = samples + (size_t)row * 4095;
        float* __restrict__ mr = ms      + (size_t)row * 4094;
        float* __restrict__ cr = scales  + (size_t)row * 4094;

        // ---- prefetch this row's noise (overlaps prev row's store drain) --
        const float nzs = nr[tid];                   // phase A (tree idx tid)
        const float n8  = nr[254 + tid];
        const f2_  n9   = *(const f2_*)(nr + 510 + 2 * tid);
        const f2_  nA0  = *(const f2_*)(nr + 1022 + 4 * tid);
        const f2_  nA1  = *(const f2_*)(nr + 1022 + 4 * tid + 2);
        f2_ nL[4];
        #pragma unroll
        for (int k = 0; k < 4; ++k)
            nL[k] = *(const f2_*)(nr + 2046 + 8 * tid + 2 * k);
        const float rootv = noise_root[row];         // IN_SCALE == 1.0

        if (tid == 0) { sL[254] = rootv; sr[4094] = rootv; }
        lgkm_barrier();

        // ---- phase A: levels 1..7 in LDS ----
        #pragma unroll
        for (int d = 1; d <= 7; ++d) {
            const int off     = (1 << d) - 2;
            const int n       = 1 << d;
            const int colbase = 4096 - (n << 1);
            if (tid >= off && tid < off + n) {
                const int c = colbase + (tid - off);
                const float p  = sL[(c >> 1) - 1792];    // parent col - 3840
                const float mv = wA * p;
                const float v  = fmaf(scA, nzs, mv);
                sL[c - 3840] = v;
                sr[c] = v; mr[c] = mv; cr[c] = scA;
            }
            lgkm_barrier();
        }

        // ---- phase B: per-thread subtree (levels 8..11), barrier-free ----
        const float a7 = sL[tid >> 1];               // level-7 ancestor

        // level 8: col 3584+tid
        const float m8 = w8 * a7;
        const float v8 = fmaf(c8, n8, m8);
        sr[3584 + tid] = v8; mr[3584 + tid] = m8; cr[3584 + tid] = c8;

        // level 9: cols 3072+2t (contiguous 2)
        const float m90 = w90 * v8, m91 = w91 * v8;
        const float v90 = fmaf(c90, n9.x, m90);
        const float v91 = fmaf(c91, n9.y, m91);
        {
            f2_ sv; sv.x = v90; sv.y = v91;
            f2_ mv; mv.x = m90; mv.y = m91;
            f2_ cv; cv.x = c90; cv.y = c91;
            *(f2u*)(sr + 3072 + 2 * tid) = sv;
            *(f2_*)(mr + 3072 + 2 * tid) = mv;   // even flat idx: 8B-aligned
            *(f2_*)(cr + 3072 + 2 * tid) = cv;
        }

        // level 10: cols 2048+4t (contiguous 4)
        const float mA0 = wa0 * v90, mA1 = wa1 * v90;
        const float mA2 = wa2 * v91, mA3 = wa3 * v91;
        const float vA0 = fmaf(ca0, nA0.x, mA0);
        const float vA1 = fmaf(ca1, nA0.y, mA1);
        const float vA2 = fmaf(ca2, nA1.x, mA2);
        const float vA3 = fmaf(ca3, nA1.y, mA3);
        {
            f4_ sv; sv.x = vA0; sv.y = vA1; sv.z = vA2; sv.w = vA3;
            f4_ mv; mv.x = mA0; mv.y = mA1; mv.z = mA2; mv.w = mA3;
            f4_ cv; cv.x = ca0; cv.y = ca1; cv.z = ca2; cv.w = ca3;
            *(f4u*)(sr + 2048 + 4 * tid) = sv;
            *(f4u*)(mr + 2048 + 4 * tid) = mv;
            *(f4u*)(cr + 2048 + 4 * tid) = cv;
        }

        // level 11: cols 8t (contiguous 8)
        const float pv[4] = { vA0, vA1, vA2, vA3 };
        float sv[8], mv[8], cv[8];
        #pragma unroll
        for (int k = 0; k < 4; ++k) {
            const float p  = pv[k];
            const float m0 = wb[2 * k] * p, m1 = wb[2 * k + 1] * p;
            sv[2 * k]     = fmaf(cb[2 * k],     nL[k].x, m0);
            sv[2 * k + 1] = fmaf(cb[2 * k + 1], nL[k].y, m1);
            mv[2 * k] = m0;          mv[2 * k + 1] = m1;
            cv[2 * k] = cb[2 * k];   cv[2 * k + 1] = cb[2 * k + 1];
        }
        {
            f4_ a, b;
            a.x = sv[0]; a.y = sv[1]; a.z = sv[2]; a.w = sv[3];
            b.x = sv[4]; b.y = sv[5]; b.z = sv[6]; b.w = sv[7];
            *(f4u*)(sr + 8 * tid)     = a;
            *(f4u*)(sr + 8 * tid + 4) = b;
            a.x = mv[0]; a.y = mv[1]; a.z = mv[2]; a.w = mv[3];
            b.x = mv[4]; b.y = mv[5]; b.z = mv[6]; b.w = mv[7];
            *(f4u*)(mr + 8 * tid)     = a;
            *(f4u*)(mr + 8 * tid + 4) = b;
            a.x = cv[0]; a.y = cv[1]; a.z = cv[2]; a.w = cv[3];
            b.x = cv[4]; b.y = cv[5]; b.z = cv[6]; b.w = cv[7];
            *(f4u*)(cr + 8 * tid)     = a;
            *(f4u*)(cr + 8 * tid + 4) = b;
        }
    }
}

extern "C" void kernel_launch(void* const* d_in, const int* in_sizes, int n_in,
                              void* d_out, int out_size, void* d_ws, size_t ws_size,
                              hipStream_t stream)
{
    const float* weights    = (const float*)d_in[0];
    const float* noise_root = (const float*)d_in[1];
    const float* noise_rest = (const float*)d_in[2];

    float* out     = (float*)d_out;
    float* samples = out;
    float* ms      = samples + (size_t)kRows * 4095;
    float* scales  = ms      + (size_t)kRows * 4094;

    lgt_fused<<<kRows / kRPB, 256, 0, stream>>>(weights, noise_root, noise_rest,
                                                samples, ms, scales);
}

// Round 12
// 120.231 us; speedup vs baseline: 1.2893x; 1.0289x over previous
//
#include <hip/hip_runtime.h>

// LinearGaussianTree, MI355X. 8192 rows; per row a 4095-node binary tree:
// s_i = w_i * s_parent + (1-w_i)*SCALE*noise_i. Outputs fp32 flat:
// samples (8192x4095), ms (8192x4094), scales (8192x4094), reverse level
// order; root = samples col 4094. Column identity: parent = (c>>1)+2048.
//
// FINAL (= r5, best measured 120.4 us over 10 structural variants):
// levels 1..7 (254 nodes) cooperatively in LDS with lgkm-only barriers
// (no vmcnt drain -> stores stay in flight across all levels); levels 8..11
// as per-thread SUBTREES (thread t owns level-8 node t and its 2+4+8
// descendants): zero barriers, zero LDS, contiguous per-thread columns ->
// dwordx2/x4 stores, float4 table loads, float2 noise loads. Whole-row noise
// prefetched at block start (one latency for everything).
//
// Measured wall: 536 MB compulsory traffic at ~4.5 TB/s effective. Variants
// tested & rejected: vmcnt-draining barriers (+24us), 4-row/64KB-LDS blocks
// (+32us), level-split kernels (+10us), stream-purity 3-kernel split (+19us),
// zero-sync shfl-redundant (+21us), nontemporal hints (+35us), fused
// persistent single-launch (+3us, noise).

constexpr int   kRows  = 8192;
constexpr float kScale = 0.1f;

typedef float f4_ __attribute__((ext_vector_type(4)));
typedef float f2_ __attribute__((ext_vector_type(2)));
typedef f4_ f4u __attribute__((aligned(4)));   // 16B vector, 4B-aligned ok
typedef f2_ f2u __attribute__((aligned(4)));

// Column-ordered (w, sc) table. Zero-init BSS; rewritten every launch.
__device__ __align__(16) float2 g_tab[4096];

__global__ __launch_bounds__(256) void lgt_precompute(
    const float* __restrict__ weights)
{
    int t = blockIdx.x * 256 + threadIdx.x;      // tree index 0..4093
    if (t < 4094) {
        int d = 31 - __clz(t + 2);               // level of node t
        int c = t + 4098 - 3 * (1 << d);         // output column
        float w = 1.0f / (1.0f + __expf(-weights[t]));
        g_tab[c] = make_float2(w, (1.0f - w) * kScale);
    }
}

// Barrier that does NOT drain vmcnt: LDS visibility only, so global
// stores/loads issued before it remain in flight.
__device__ __forceinline__ void lgkm_barrier() {
    __builtin_amdgcn_sched_barrier(0);
    asm volatile("s_waitcnt lgkmcnt(0)" ::: "memory");
    __builtin_amdgcn_s_barrier();
    __builtin_amdgcn_sched_barrier(0);
}

__global__ __launch_bounds__(256) void lgt_main(
    const float* __restrict__ noise_root,
    const float* __restrict__ noise_rest,
    float* __restrict__ samples,
    float* __restrict__ ms,
    float* __restrict__ scales)
{
    __shared__ float sL[256];                    // cols 3840..4095 (root @254)

    const int row = blockIdx.x;
    const int tid = threadIdx.x;
    const float* __restrict__ nr = noise_rest + (size_t)row * 4094;
    float* __restrict__ sr = samples + (size_t)row * 4095;
    float* __restrict__ mr = ms      + (size_t)row * 4094;
    float* __restrict__ cr = scales  + (size_t)row * 4094;

    // ---- prefetch all of this row's noise (one latency for everything) ----
    // nr is 8B-aligned (base 16B + row*16376), all f2_ offsets even.
    const float nzs = nr[tid];                   // levels 1..7: tree idx == tid
    const float n8  = nr[254 + tid];             // level 8 (node tid)
    const f2_  n9   = *(const f2_*)(nr + 510 + 2 * tid);
    const f2_  nA0  = *(const f2_*)(nr + 1022 + 4 * tid);
    const f2_  nA1  = *(const f2_*)(nr + 1022 + 4 * tid + 2);
    f2_ nL[4];
    #pragma unroll
    for (int k = 0; k < 4; ++k)
        nL[k] = *(const f2_*)(nr + 2046 + 8 * tid + 2 * k);
    const float rootv = noise_root[row];         // IN_SCALE == 1.0

    if (tid == 0) { sL[254] = rootv; sr[4094] = rootv; }
    lgkm_barrier();

    // ---- phase A: levels 1..7 in LDS (254 nodes, 8 lgkm barriers) ----
    #pragma unroll
    for (int d = 1; d <= 7; ++d) {
        const int off     = (1 << d) - 2;
        const int n       = 1 << d;
        const int colbase = 4096 - (n << 1);
        if (tid >= off && tid < off + n) {
            const int c = colbase + (tid - off);
            const float2 t2 = g_tab[c];
            const float  p  = sL[(c >> 1) - 1792];   // parent col - 3840
            const float  mv = t2.x * p;
            const float  v  = fmaf(t2.y, nzs, mv);
            sL[c - 3840] = v;
            sr[c] = v; mr[c] = mv; cr[c] = t2.y;
        }
        lgkm_barrier();
    }

    // ---- phase B: per-thread subtree, barrier-free ----
    const float a7 = sL[tid >> 1];               // level-7 ancestor (broadcast)

    // level 8: node tid, col 3584+tid
    const float2 t8 = g_tab[3584 + tid];
    const float  m8 = t8.x * a7;
    const float  v8 = fmaf(t8.y, n8, m8);
    sr[3584 + tid] = v8; mr[3584 + tid] = m8; cr[3584 + tid] = t8.y;

    // level 9: nodes 2t,2t+1 -> cols 3072+2t (contiguous 2)
    const f4_ t9 = *(const f4_*)(&g_tab[3072 + 2 * tid]);   // 16B-aligned
    const float m90 = t9.x * v8, m91 = t9.z * v8;
    const float v90 = fmaf(t9.y, n9.x, m90);
    const float v91 = fmaf(t9.w, n9.y, m91);
    {
        f2_ sv; sv.x = v90; sv.y = v91;
        f2_ mv; mv.x = m90; mv.y = m91;
        f2_ cv; cv.x = t9.y; cv.y = t9.w;
        *(f2u*)(sr + 3072 + 2 * tid) = sv;       // row base only 4B-aligned
        *(f2_*)(mr + 3072 + 2 * tid) = mv;       // even flat idx: 8B-aligned
        *(f2_*)(cr + 3072 + 2 * tid) = cv;
    }

    // level 10: nodes 4t..4t+3 -> cols 2048+4t (contiguous 4)
    const f4_ tA = *(const f4_*)(&g_tab[2048 + 4 * tid]);
    const f4_ tB = *(const f4_*)(&g_tab[2048 + 4 * tid + 2]);
    const float mA0 = tA.x * v90, mA1 = tA.z * v90;
    const float mB0 = tB.x * v91, mB1 = tB.z * v91;
    const float vA0 = fmaf(tA.y, nA0.x, mA0);
    const float vA1 = fmaf(tA.w, nA0.y, mA1);
    const float vB0 = fmaf(tB.y, nA1.x, mB0);
    const float vB1 = fmaf(tB.w, nA1.y, mB1);
    {
        f4_ sv; sv.x = vA0; sv.y = vA1; sv.z = vB0; sv.w = vB1;
        f4_ mv; mv.x = mA0; mv.y = mA1; mv.z = mB0; mv.w = mB1;
        f4_ cv; cv.x = tA.y; cv.y = tA.w; cv.z = tB.y; cv.w = tB.w;
        *(f4u*)(sr + 2048 + 4 * tid) = sv;
        *(f4u*)(mr + 2048 + 4 * tid) = mv;
        *(f4u*)(cr + 2048 + 4 * tid) = cv;
    }

    // level 11: nodes 8t..8t+7 -> cols 8t (contiguous 8)
    const float pv0 = vA0, pv1 = vA1, pv2 = vB0, pv3 = vB1;
    float sv[8], mv[8], cv[8];
    #pragma unroll
    for (int k = 0; k < 4; ++k) {
        const f4_  t = *(const f4_*)(&g_tab[8 * tid + 2 * k]);  // 16B-aligned
        const float p = (k == 0) ? pv0 : (k == 1) ? pv1 : (k == 2) ? pv2 : pv3;
        const float m0 = t.x * p, m1 = t.z * p;
        sv[2 * k]     = fmaf(t.y, nL[k].x, m0);
        sv[2 * k + 1] = fmaf(t.w, nL[k].y, m1);
        mv[2 * k] = m0; mv[2 * k + 1] = m1;
        cv[2 * k] = t.y; cv[2 * k + 1] = t.w;
    }
    {
        f4_ a, b;
        a.x = sv[0]; a.y = sv[1]; a.z = sv[2]; a.w = sv[3];
        b.x = sv[4]; b.y = sv[5]; b.z = sv[6]; b.w = sv[7];
        *(f4u*)(sr + 8 * tid)     = a;
        *(f4u*)(sr + 8 * tid + 4) = b;
        a.x = mv[0]; a.y = mv[1]; a.z = mv[2]; a.w = mv[3];
        b.x = mv[4]; b.y = mv[5]; b.z = mv[6]; b.w = mv[7];
        *(f4u*)(mr + 8 * tid)     = a;
        *(f4u*)(mr + 8 * tid + 4) = b;
        a.x = cv[0]; a.y = cv[1]; a.z = cv[2]; a.w = cv[3];
        b.x = cv[4]; b.y = cv[5]; b.z = cv[6]; b.w = cv[7];
        *(f4u*)(cr + 8 * tid)     = a;
        *(f4u*)(cr + 8 * tid + 4) = b;
    }
}

extern "C" void kernel_launch(void* const* d_in, const int* in_sizes, int n_in,
                              void* d_out, int out_size, void* d_ws, size_t ws_size,
                              hipStream_t stream)
{
    const float* weights    = (const float*)d_in[0];
    const float* noise_root = (const float*)d_in[1];
    const float* noise_rest = (const float*)d_in[2];

    float* out     = (float*)d_out;
    float* samples = out;
    float* ms      = samples + (size_t)kRows * 4095;
    float* scales  = ms      + (size_t)kRows * 4094;

    lgt_precompute<<<(4094 + 255) / 256, 256, 0, stream>>>(weights);
    lgt_main<<<kRows, 256, 0, stream>>>(noise_root, noise_rest,
                                        samples, ms, scales);
}